// Round 18
// baseline (60.803 us; speedup 1.0000x reference)
//
#include <hip/hip_runtime.h>
#include <hip/hip_bf16.h>

#define NROWS 8192
#define DIM 256
#define NSPLIT 16
#define JSPAN (NROWS / NSPLIT)   /* 512 cols per block */
#define TILE_COLS 64
#define TILE_BYTES (TILE_COLS * 512)  /* 32 KB */
#define NT (JSPAN / TILE_COLS)   /* 8 tiles per block */
#define RPW 64                   /* rows per wave (A stationary) */
#define RPB 512                  /* rows per block (8 waves) */
#define GRP32_BYTES 16384        /* 32 cols x 512 B, K-major-grouped */

typedef __bf16 bf16x8 __attribute__((ext_vector_type(8)));
typedef float f32x16 __attribute__((ext_vector_type(16)));

#define NEG_LOG2E -1.4426950408889634f
#define NEG_LN2   -0.6931471805599453f

// ---- Kernel 1: L2-normalize rows, fp32 -> bf16; zero accums ----
// En: row-major, scaled by -log2(e) (GEMM acc = -log2e*sim; exp(-sim)=exp2(acc)).
// Qn: 32-col K-MAJOR-GROUPED for the 32x32x16 B fragment. Group g = cols
// [32g,32g+32); chunk kk (1 KB) = the 32 cols' k-slice [16kk,16kk+16),
// col-interleaved at 32B: byte(col=32g+c, k) =
//   g*16384 + (k/16)*1024 + c*32 + (k%16)*2.
// DMA = contiguous identity copy; B ds_read: lane reads 16B at
// c*32 + (lane>>5)*16 -> 64 distinct 16B slots per 1KB chunk (conflict-free).
__global__ __launch_bounds__(256) void k_normalize_all(const float* __restrict__ emb,
                                                       const float* __restrict__ qry,
                                                       __hip_bfloat16* __restrict__ En,
                                                       __hip_bfloat16* __restrict__ Qn,
                                                       float* __restrict__ rowsum,
                                                       float* __restrict__ out) {
    if (blockIdx.x < 8)
        reinterpret_cast<float4*>(rowsum)[blockIdx.x * 256 + threadIdx.x] =
            float4{0.f, 0.f, 0.f, 0.f};
    if (blockIdx.x == 8 && threadIdx.x == 0) out[0] = 0.f;

    const int gr   = blockIdx.x * 4 + (threadIdx.x >> 6);
    const int lane = threadIdx.x & 63;
    const bool isE = (gr < NROWS);
    const float* in = isE ? emb : qry;
    const int row   = isE ? gr : gr - NROWS;
    const float scale = isE ? NEG_LOG2E : 1.0f;

    const float4 v = reinterpret_cast<const float4*>(in + (size_t)row * DIM)[lane];
    float ss = v.x * v.x + v.y * v.y + v.z * v.z + v.w * v.w;
#pragma unroll
    for (int m = 32; m >= 1; m >>= 1) ss += __shfl_xor(ss, m, 64);
    const float inv = scale / fmaxf(sqrtf(ss), 1e-8f);
    __hip_bfloat16 o[4];
    o[0] = __float2bfloat16(v.x * inv);
    o[1] = __float2bfloat16(v.y * inv);
    o[2] = __float2bfloat16(v.z * inv);
    o[3] = __float2bfloat16(v.w * inv);
    const ushort4 o8 = *reinterpret_cast<const ushort4*>(o);

    if (isE) {
        reinterpret_cast<ushort4*>(En + (size_t)row * DIM)[lane] = o8;
    } else {
        // Lane holds k = lane*4 .. lane*4+3 of this col (8 bytes).
        const int g = row >> 5, c = row & 31;
        char* dst = (char*)Qn + (size_t)g * GRP32_BYTES
                    + (size_t)(lane >> 2) * 1024 + c * 32 + (lane & 3) * 8;
        *reinterpret_cast<ushort4*>(dst) = o8;
    }
}

// ---- Kernel 2: fused sim-GEMM + row sum of exp(-s), 32x32x16 MFMA ----
// r15's proven safe structure (8 waves x 64 rows, shared 64-col tile, ring-2
// LDS, stage-at-top, ONE vmcnt(0)+barrier per tile - no per-phase barriers,
// which produced a 17ms pathological outlier in r17). Shape change only:
// v_mfma_f32_32x32x16_bf16 halves MFMA instruction count (32-cy ops -> fewer
// dependency boundaries) and raises the ceiling 2176->2495 TF.
// A frag: row=lane&31, k=(lane>>5)*8+e. B frag: col=lane&31, same k.
// C/D: col=lane&31, row=(r&3)+8*(r>>2)+4*(lane>>5), r=0..15 (m74/m101).
__global__ __launch_bounds__(512, 2) void k_simlse(const __hip_bfloat16* __restrict__ En,
                                                   const __hip_bfloat16* __restrict__ Qn,
                                                   float* __restrict__ rowsum,
                                                   float* __restrict__ pickv) {
    __shared__ char lds[2][TILE_BYTES];   // 64 KB ring-2
    const int bx   = blockIdx.x;
    const int ib   = bx >> 4;            // 0..15
    const int jq   = bx & 15;
    const int tid  = threadIdx.x;
    const int lane = tid & 63;
    const int w    = tid >> 6;           // wave 0..7
    const int l31  = lane & 31;
    const int hi   = lane >> 5;          // k-half 0..1
    const int i0w  = ib * RPB + w * RPW;

    // A fragments: 64 rows (2 row-tiles of 32) x K=256 -> a[2][16] (128 regs).
    bf16x8 a[2][16];
    {
        const __hip_bfloat16* ab = En + (size_t)(i0w + l31) * DIM + hi * 8;
#pragma unroll
        for (int rt = 0; rt < 2; ++rt)
#pragma unroll
            for (int kk = 0; kk < 16; ++kk)
                a[rt][kk] = *reinterpret_cast<const bf16x8*>(ab + rt * 32 * DIM + kk * 16);
    }

    float racc[2][16];
#pragma unroll
    for (int rt = 0; rt < 2; ++rt)
#pragma unroll
        for (int r = 0; r < 16; ++r) racc[rt][r] = 0.0f;

    const int jq0 = jq * JSPAN;
    // Wave w stages chunks [4w, 4w+4) of each 32-chunk tile (identity copy).
    const char* qtile = (const char*)Qn + (size_t)jq0 * 512 + (size_t)lane * 16
                        + (size_t)w * 4096;

    auto stage_tile = [&](const char* src, char* buf) {
#pragma unroll
        for (int i = 0; i < 4; ++i)
            __builtin_amdgcn_global_load_lds(
                (const __attribute__((address_space(1))) void*)(src + i * 1024),
                (__attribute__((address_space(3))) void*)(buf + w * 4096 + i * 1024),
                16, 0, 0);
    };

    // Prologue: stage tile 0, drain own 4 DMAs, barrier.
    stage_tile(qtile, lds[0]);
    asm volatile("s_waitcnt vmcnt(0)" ::: "memory");
    __builtin_amdgcn_s_barrier();

    for (int t = 0; t < NT; ++t) {
        const char* cur = lds[t & 1];
        char* nxt       = lds[(t + 1) & 1];
        if (t + 1 < NT) stage_tile(qtile + TILE_BYTES, nxt);
        qtile += TILE_BYTES;

        // Conflict-free fragment base: 16B at c*32 + hi*16 within each chunk.
        const char* rd = cur + l31 * 32 + hi * 16;
        const int tbase = jq0 + t * TILE_COLS;

#pragma unroll
        for (int gg = 0; gg < 2; ++gg) {     // two 32-col groups per tile
            f32x16 acc0 = {0.f}, acc1 = {0.f};

            __builtin_amdgcn_s_setprio(1);
#pragma unroll
            for (int kk = 0; kk < 16; ++kk) {
                const bf16x8 b = *reinterpret_cast<const bf16x8*>(
                    rd + gg * GRP32_BYTES + kk * 1024);
                acc0 = __builtin_amdgcn_mfma_f32_32x32x16_bf16(a[0][kk], b, acc0, 0, 0, 0);
                acc1 = __builtin_amdgcn_mfma_f32_32x32x16_bf16(a[1][kk], b, acc1, 0, 0, 0);
            }
            __builtin_amdgcn_s_setprio(0);

            // Epilogue. acc = -log2e*s; exp(-s) = exp2(acc).
            const int grpbase = tbase + gg * 32;
            const int jg = grpbase + l31;
            const bool spec = (grpbase <= i0w + RPW) && (grpbase + 32 > i0w);
            if (!spec) {
#pragma unroll
                for (int r = 0; r < 16; ++r) {
                    racc[0][r] += __builtin_amdgcn_exp2f(acc0[r]);
                    racc[1][r] += __builtin_amdgcn_exp2f(acc1[r]);
                }
            } else {
#pragma unroll
                for (int rt = 0; rt < 2; ++rt) {
                    const int ig0 = i0w + rt * 32 + 4 * hi;
#pragma unroll
                    for (int r = 0; r < 16; ++r) {
                        const float av = (rt == 0) ? acc0[r] : acc1[r];
                        const float e  = __builtin_amdgcn_exp2f(av);
                        const int   ig = ig0 + (r & 3) + 8 * (r >> 2);
                        racc[rt][r] += (jg == ig) ? 0.0f : e;
                        const int pc = (ig == NROWS - 1) ? (NROWS - 2) : (ig + 1);
                        if (jg == pc) pickv[ig] = av * NEG_LN2;  // recover s
                    }
                }
            }
        }

        if (t + 1 < NT) {
            // Own DMAs for tile t+1 were issued ~2 groups (~2000 cy) ago.
            asm volatile("s_waitcnt vmcnt(0)" ::: "memory");
            __builtin_amdgcn_s_barrier();
        }
    }

    // Reduce row partials across the 32 col-lanes, one atomicAdd per row.
#pragma unroll
    for (int rt = 0; rt < 2; ++rt)
#pragma unroll
        for (int r = 0; r < 16; ++r) {
            float v = racc[rt][r];
            v += __shfl_xor(v, 1, 64);
            v += __shfl_xor(v, 2, 64);
            v += __shfl_xor(v, 4, 64);
            v += __shfl_xor(v, 8, 64);
            v += __shfl_xor(v, 16, 64);
            if (l31 == 0)
                atomicAdd(&rowsum[i0w + rt * 32 + (r & 3) + 8 * (r >> 2) + 4 * hi], v);
        }
}

// ---- Kernel 3: final reduce, 16 blocks, one atomicAdd each (out pre-zeroed) ----
__global__ __launch_bounds__(256) void k_finalize(const float* __restrict__ rowsum,
                                                  const float* __restrict__ pickv,
                                                  float* __restrict__ out) {
    __shared__ float red[4];
    const int base = blockIdx.x * 512;
    float s = 0.0f;
#pragma unroll
    for (int it = 0; it < 2; ++it) {
        const int i = base + it * 256 + threadIdx.x;
        s += __logf(rowsum[i]) + pickv[i];
    }
#pragma unroll
    for (int m = 32; m >= 1; m >>= 1) s += __shfl_xor(s, m, 64);
    if ((threadIdx.x & 63) == 0) red[threadIdx.x >> 6] = s;
    __syncthreads();
    if (threadIdx.x == 0)
        atomicAdd(out, (red[0] + red[1] + red[2] + red[3]) * (1.0f / (float)NROWS));
}

extern "C" void kernel_launch(void* const* d_in, const int* in_sizes, int n_in,
                              void* d_out, int out_size, void* d_ws, size_t ws_size,
                              hipStream_t stream) {
    const float* emb = (const float*)d_in[0];
    const float* qry = (const float*)d_in[1];
    float* out = (float*)d_out;

    char* ws = (char*)d_ws;
    __hip_bfloat16* En = (__hip_bfloat16*)ws;                                  // 4 MB row-major
    __hip_bfloat16* Qn = (__hip_bfloat16*)(ws + (size_t)NROWS * DIM * 2);      // 4 MB 32-col K-major-grouped
    float* rowsum = (float*)(ws + (size_t)NROWS * DIM * 4);                    // 32 KB
    float* pickv  = rowsum + NROWS;                                            // 32 KB

    k_normalize_all<<<2 * NROWS / 4, 256, 0, stream>>>(emb, qry, En, Qn, rowsum, out);
    k_simlse<<<16 * NSPLIT, 512, 0, stream>>>(En, Qn, rowsum, pickv);
    k_finalize<<<16, 256, 0, stream>>>(rowsum, pickv, out);
}